// Round 5
// baseline (469.561 us; speedup 1.0000x reference)
//
#include <hip/hip_runtime.h>
#include <cstdint>
#include <cstddef>

typedef _Float16 f16;
typedef f16 f16x8 __attribute__((ext_vector_type(8)));
typedef float f32x4 __attribute__((ext_vector_type(4)));
typedef float f32x16 __attribute__((ext_vector_type(16)));

#define B_ROWS 65536
#define NT_BRANCH 1030   // 64-row bins: 1024 + 6 bins' padding
#define NT_BR32 2060     // 32-row branch tiles
#define NT_SP32 2048     // 32-row speed tiles

// ---------------- ws layout ----------------
constexpr size_t OFF_SF16   = 0;
constexpr size_t SZ_SF16    = (size_t)B_ROWS * 128 * 2;
constexpr size_t OFF_SIW2T  = OFF_SF16 + SZ_SF16;
constexpr size_t SZ_SIW2T   = (size_t)128 * 256 * 2;
constexpr size_t OFF_BW1T   = OFF_SIW2T + SZ_SIW2T;
constexpr size_t SZ_BW1T    = (size_t)6 * 256 * 640 * 2;
constexpr size_t OFF_BW2T   = OFF_BW1T + SZ_BW1T;
constexpr size_t SZ_BW2T    = (size_t)6 * 256 * 256 * 2;
constexpr size_t OFF_SOW1T  = OFF_BW2T + SZ_BW2T;
constexpr size_t SZ_SOW1T   = (size_t)256 * 640 * 2;
constexpr size_t OFF_SOW2T  = OFF_SOW1T + SZ_SOW1T;
constexpr size_t SZ_SOW2T   = (size_t)256 * 256 * 2;
constexpr size_t OFF_BW3T16 = OFF_SOW2T + SZ_SOW2T;
constexpr size_t SZ_BW3T16  = (size_t)6 * 16 * 256 * 2;
constexpr size_t OFF_SOW3T16= OFF_BW3T16 + SZ_BW3T16;
constexpr size_t SZ_SOW3T16 = (size_t)16 * 256 * 2;
constexpr size_t OFF_COUNTS = OFF_SOW3T16 + SZ_SOW3T16;
constexpr size_t OFF_CURSORS= OFF_COUNTS + 256;
constexpr size_t OFF_TILECMD= OFF_CURSORS + 256;
constexpr size_t OFF_PERM   = OFF_TILECMD + 8448;              // NT_BR32*4 padded
constexpr size_t WS_NEEDED  = OFF_PERM + (size_t)NT_BRANCH * 64 * 4;

// ---------------- prep: transpose-cast weights + W3T16 + init sort scratch ----------------
__global__ void prep_kernel(const float* __restrict__ siW2,
                            const float* __restrict__ bW1,
                            const float* __restrict__ bW2,
                            const float* __restrict__ soW1,
                            const float* __restrict__ soW2,
                            const float* __restrict__ bW3,
                            const float* __restrict__ soW3,
                            f16* __restrict__ siW2T, f16* __restrict__ bW1T,
                            f16* __restrict__ bW2T, f16* __restrict__ soW1T,
                            f16* __restrict__ soW2T,
                            f16* __restrict__ bW3T16, f16* __restrict__ soW3T16,
                            int* __restrict__ counts, int* __restrict__ cursors,
                            int* __restrict__ perm)
{
    const int bx = blockIdx.x;
    const int tx = threadIdx.x, ty = threadIdx.y;
    const int tid = ty * 32 + tx;
    if (bx >= 1601) {                       // perm init + counter zero
        const int ib = bx - 1601;
        const int idx = ib * 256 + tid;
        if (idx < NT_BRANCH * 64) perm[idx] = -1;
        if (ib == 0 && tid < 6) { counts[tid] = 0; cursors[tid] = 0; }
        return;
    }
    if (bx == 1600) {                       // W3 -> padded-16-col f16, [n][k] layout
        for (int i = tid; i < 6 * 16 * 256; i += 256) {
            const int c = i >> 12, rem = i & 4095, n = rem >> 8, k = rem & 255;
            bW3T16[i] = (n < 3) ? (f16)bW3[((size_t)c * 256 + k) * 3 + n] : (f16)0;
        }
        for (int i = tid; i < 16 * 256; i += 256) {
            const int n = i >> 8, k = i & 255;
            soW3T16[i] = (n == 0) ? (f16)soW3[k] : (f16)0;
        }
        return;
    }
    const float* in; f16* out; int R, C, lb;
    if (bx < 960)       { int m = bx / 160;        lb = bx - m * 160;       in = bW1 + (size_t)m * 640 * 256; out = bW1T + (size_t)m * 640 * 256; R = 640; C = 256; }
    else if (bx < 1344) { int m = (bx - 960) / 64; lb = (bx - 960) - m * 64; in = bW2 + (size_t)m * 256 * 256; out = bW2T + (size_t)m * 256 * 256; R = 256; C = 256; }
    else if (bx < 1504) { lb = bx - 1344; in = soW1; out = soW1T; R = 640; C = 256; }
    else if (bx < 1568) { lb = bx - 1504; in = soW2; out = soW2T; R = 256; C = 256; }
    else                { lb = bx - 1568; in = siW2; out = siW2T; R = 256; C = 128; }
    const int txt = C >> 5;
    const int c0 = (lb % txt) << 5;
    const int r0 = (lb / txt) << 5;
    __shared__ float tile[32][33];
    #pragma unroll
    for (int i = 0; i < 4; ++i)
        tile[tx][ty + 8 * i] = in[(size_t)(r0 + ty + 8 * i) * C + c0 + tx];
    __syncthreads();
    #pragma unroll
    for (int i = 0; i < 4; ++i)
        out[(size_t)(c0 + ty + 8 * i) * R + r0 + tx] = (f16)tile[ty + 8 * i][tx];
}

// ---------------- speed_in MLP (+ fused histogram) ----------------
__global__ __launch_bounds__(256) void speedin_kernel(
    const float* __restrict__ speed,
    const float* __restrict__ siW1, const float* __restrict__ sib1,
    const f16* __restrict__ siW2T, const float* __restrict__ sib2,
    const int* __restrict__ cmd,
    f16* __restrict__ sF16, int* __restrict__ counts)
{
    __shared__ f16 H[64 * 264];
    __shared__ float spd[64];
    __shared__ int h[6];
    const int tid = threadIdx.x;
    const int rb = blockIdx.x * 64;
    if (tid < 6) h[tid] = 0;
    __syncthreads();
    if (tid < 64) {
        spd[tid] = speed[rb + tid];
        atomicAdd(&h[cmd[rb + tid] - 1], 1);
    }
    __syncthreads();
    if (tid < 6 && h[tid] > 0) atomicAdd(&counts[tid], h[tid]);
    {
        const float w1 = siW1[tid], b1v = sib1[tid];
        #pragma unroll 4
        for (int r = 0; r < 64; ++r) {
            float hv = spd[r] * w1 + b1v;
            H[r * 264 + tid] = (f16)(hv > 0.f ? hv : 0.f);
        }
    }
    __syncthreads();
    const int w = tid >> 6, lane = tid & 63, lq = lane >> 4, l16 = lane & 15;
    const int nb = w * 32;
    f32x4 acc[4][2];
    #pragma unroll
    for (int mt = 0; mt < 4; ++mt)
        #pragma unroll
        for (int nt = 0; nt < 2; ++nt)
            acc[mt][nt] = (f32x4){0.f, 0.f, 0.f, 0.f};
    for (int ks = 0; ks < 8; ++ks) {
        const int koff = ks * 32 + lq * 8;
        f16x8 af[4], bf[2];
        #pragma unroll
        for (int mt = 0; mt < 4; ++mt)
            af[mt] = *(const f16x8*)(&H[(mt * 16 + l16) * 264 + koff]);
        #pragma unroll
        for (int nt = 0; nt < 2; ++nt)
            bf[nt] = *(const f16x8*)(siW2T + (size_t)(nb + nt * 16 + l16) * 256 + koff);
        #pragma unroll
        for (int mt = 0; mt < 4; ++mt)
            #pragma unroll
            for (int nt = 0; nt < 2; ++nt)
                acc[mt][nt] = __builtin_amdgcn_mfma_f32_16x16x32_f16(af[mt], bf[nt], acc[mt][nt], 0, 0, 0);
    }
    #pragma unroll
    for (int mt = 0; mt < 4; ++mt)
        #pragma unroll
        for (int nt = 0; nt < 2; ++nt) {
            const int n = nb + nt * 16 + l16;
            const float bv = sib2[n];
            #pragma unroll
            for (int r2 = 0; r2 < 4; ++r2) {
                const int m = mt * 16 + lq * 4 + r2;
                sF16[(size_t)(rb + m) * 128 + n] = (f16)(acc[mt][nt][r2] + bv);
            }
        }
}

// ---------------- place (plan fused): scatter rows into bins + tile_cmd ----------------
__global__ void place_kernel(const int* __restrict__ cmd,
                             const int* __restrict__ counts,
                             int* __restrict__ cursors, int* __restrict__ perm,
                             int* __restrict__ tile_cmd) {
    __shared__ int lcnt[6], lbase[6], bb[7];
    const int tid = threadIdx.x;
    if (tid < 6) lcnt[tid] = 0;
    __syncthreads();
    const int i = blockIdx.x * 256 + tid;
    const int c = cmd[i] - 1;
    const int myr = atomicAdd(&lcnt[c], 1);
    if (tid == 0) {
        int base = 0;
        for (int c0 = 0; c0 < 6; ++c0) {
            bb[c0] = base;
            base += ((counts[c0] + 63) >> 6) << 6;
        }
        bb[6] = base;
    }
    __syncthreads();
    if (tid < 6) lbase[tid] = atomicAdd(&cursors[tid], lcnt[tid]);
    __syncthreads();
    perm[bb[c] + lbase[c] + myr] = i;
    if (blockIdx.x == 0) {
        for (int t = tid; t < NT_BR32; t += 256) {
            int cc = -1;
            #pragma unroll
            for (int j = 0; j < 6; ++j)
                if (t * 32 >= bb[j] && t * 32 < bb[j + 1]) cc = j;
            tile_cmd[t] = cc;
        }
    }
}

// ---------------- heads: M=32 tile, barrier-free K-loops ----------------
// 256 thr = 4 waves, wave w owns N-slice w*64..+63. GEMM1/2: 32x32x16, acc 2xf32x16.
// A-tile (32x640 f16) staged to LDS in one burst (18 loads/thread in flight),
// then ONE barrier; K-loops read LDS + roll B-frags 8 steps ahead in VGPRs.
__global__ __launch_bounds__(256, 3) void heads_kernel(
    const float* __restrict__ emb,        // [B,512] fp32
    const f16* __restrict__ sF16,         // [B,128]
    const int* __restrict__ perm, const int* __restrict__ tile_cmd,
    const f16* __restrict__ bW1T, const f16* __restrict__ bW2T,
    const f16* __restrict__ bW3T16,
    const float* __restrict__ bb1, const float* __restrict__ bb2,
    const float* __restrict__ bb3,
    const f16* __restrict__ soW1T, const f16* __restrict__ soW2T,
    const f16* __restrict__ soW3T16,
    const float* __restrict__ sob1, const float* __restrict__ sob2,
    const float* __restrict__ sob3,
    float* __restrict__ out)
{
    __shared__ f16 smem[32 * 644];        // A-tile [32][644]; h [32][268] aliases it
    __shared__ int rowIdx[32];
    const int bx = blockIdx.x, tid = threadIdx.x;
    const bool is_speed = (bx < NT_SP32);
    const f16 *W1T, *W2T, *W3T;
    const float *bias1, *bias2, *bias3;
    if (is_speed) {
        if (tid < 32) rowIdx[tid] = bx * 32 + tid;
        W1T = soW1T; W2T = soW2T; W3T = soW3T16;
        bias1 = sob1; bias2 = sob2; bias3 = sob3;
    } else {
        const int t = bx - NT_SP32;
        const int c = tile_cmd[t];
        if (c < 0) return;
        if (tid < 32) rowIdx[tid] = perm[t * 32 + tid];
        W1T = bW1T + (size_t)c * 256 * 640;
        W2T = bW2T + (size_t)c * 256 * 256;
        W3T = bW3T16 + (size_t)c * 16 * 256;
        bias1 = bb1 + c * 256; bias2 = bb2 + c * 256; bias3 = bb3 + c * 3;
    }
    __syncthreads();

    const int w = tid >> 6, lane = tid & 63;
    const int l32 = lane & 31, lq2 = lane >> 5;
    const int l16 = lane & 15, lq = lane >> 4;

    // ---- stage A tile 32x640 f16 into LDS; all 18 global loads issued up front
    {
        const int r = tid >> 3, p = tid & 7;
        int g = rowIdx[r]; if (g < 0) g = 0;
        const float* srcF = emb + (size_t)g * 512 + p * 8;
        const f16*   srcH = sF16 + (size_t)g * 128 + p * 8;
        float4 ra[8], rb[8];
        #pragma unroll
        for (int c = 0; c < 8; ++c) {
            ra[c] = ((const float4*)(srcF + c * 64))[0];
            rb[c] = ((const float4*)(srcF + c * 64))[1];
        }
        const f16x8 rh0 = *(const f16x8*)(srcH);
        const f16x8 rh1 = *(const f16x8*)(srcH + 64);
        f16* dst = smem + r * 644 + p * 8;
        #pragma unroll
        for (int c = 0; c < 8; ++c) {
            f16x8 v;
            v[0] = (f16)ra[c].x; v[1] = (f16)ra[c].y; v[2] = (f16)ra[c].z; v[3] = (f16)ra[c].w;
            v[4] = (f16)rb[c].x; v[5] = (f16)rb[c].y; v[6] = (f16)rb[c].z; v[7] = (f16)rb[c].w;
            *(f16x8*)(dst + c * 64) = v;
        }
        *(f16x8*)(dst + 512) = rh0;
        *(f16x8*)(dst + 576) = rh1;
    }

    // B pointers, bias prefetch, GEMM1 B prefill (8 steps deep)
    const int nq = w;
    const f16* bp0 = W1T + (size_t)(nq * 64 + l32) * 640 + lq2 * 8;
    const f16* bp1 = bp0 + (size_t)32 * 640;
    const float b1r0 = bias1[nq * 64 + l32], b1r1 = bias1[nq * 64 + 32 + l32];
    const float b2r0 = bias2[nq * 64 + l32], b2r1 = bias2[nq * 64 + 32 + l32];
    f16x8 Bb[8][2];
    #pragma unroll
    for (int si = 0; si < 8; ++si) {
        Bb[si][0] = *(const f16x8*)(bp0 + si * 16);
        Bb[si][1] = *(const f16x8*)(bp1 + si * 16);
    }
    __syncthreads();                      // A tile ready (single staging drain)

    // ---- GEMM1: K=640 = 40 steps of 32x32x16, no barriers
    f32x16 acc0, acc1;
    #pragma unroll
    for (int i = 0; i < 16; ++i) { acc0[i] = 0.f; acc1[i] = 0.f; }
    const f16* aBase = smem + l32 * 644 + lq2 * 8;
    #pragma unroll 1
    for (int sb = 0; sb < 4; ++sb) {
        #pragma unroll
        for (int si = 0; si < 8; ++si) {
            const int s = sb * 8 + si;
            const f16x8 a = *(const f16x8*)(aBase + s * 16);
            acc0 = __builtin_amdgcn_mfma_f32_32x32x16_f16(a, Bb[si][0], acc0, 0, 0, 0);
            acc1 = __builtin_amdgcn_mfma_f32_32x32x16_f16(a, Bb[si][1], acc1, 0, 0, 0);
            Bb[si][0] = *(const f16x8*)(bp0 + (s + 8) * 16);
            Bb[si][1] = *(const f16x8*)(bp1 + (s + 8) * 16);
        }
    }
    #pragma unroll
    for (int si = 0; si < 8; ++si) {
        const int s = 32 + si;
        const f16x8 a = *(const f16x8*)(aBase + s * 16);
        acc0 = __builtin_amdgcn_mfma_f32_32x32x16_f16(a, Bb[si][0], acc0, 0, 0, 0);
        acc1 = __builtin_amdgcn_mfma_f32_32x32x16_f16(a, Bb[si][1], acc1, 0, 0, 0);
    }
    __syncthreads();                      // all GEMM1 LDS reads done before h1 overwrite

    // GEMM2 B prefill (ages across the h1 epilogue)
    const f16* cp0 = W2T + (size_t)(nq * 64 + l32) * 256 + lq2 * 8;
    const f16* cp1 = cp0 + (size_t)32 * 256;
    f16x8 Cb[8][2];
    #pragma unroll
    for (int si = 0; si < 8; ++si) {
        Cb[si][0] = *(const f16x8*)(cp0 + si * 16);
        Cb[si][1] = *(const f16x8*)(cp1 + si * 16);
    }

    // h1 = relu(acc + b1) -> smem[32][268]  (32x32 C-layout)
    #pragma unroll
    for (int rg = 0; rg < 16; ++rg) {
        const int m = (rg & 3) + 8 * (rg >> 2) + 4 * lq2;
        const float v0 = acc0[rg] + b1r0;
        const float v1 = acc1[rg] + b1r1;
        smem[m * 268 + nq * 64 + l32]      = (f16)(v0 > 0.f ? v0 : 0.f);
        smem[m * 268 + nq * 64 + 32 + l32] = (f16)(v1 > 0.f ? v1 : 0.f);
    }
    __syncthreads();

    // ---- GEMM2: K=256 = 16 steps, no barriers
    f32x16 d0, d1;
    #pragma unroll
    for (int i = 0; i < 16; ++i) { d0[i] = 0.f; d1[i] = 0.f; }
    const f16* hBase = smem + l32 * 268 + lq2 * 8;
    #pragma unroll
    for (int si = 0; si < 8; ++si) {
        const f16x8 a = *(const f16x8*)(hBase + si * 16);
        d0 = __builtin_amdgcn_mfma_f32_32x32x16_f16(a, Cb[si][0], d0, 0, 0, 0);
        d1 = __builtin_amdgcn_mfma_f32_32x32x16_f16(a, Cb[si][1], d1, 0, 0, 0);
        Cb[si][0] = *(const f16x8*)(cp0 + (si + 8) * 16);
        Cb[si][1] = *(const f16x8*)(cp1 + (si + 8) * 16);
    }
    #pragma unroll
    for (int si = 0; si < 8; ++si) {
        const f16x8 a = *(const f16x8*)(hBase + (8 + si) * 16);
        d0 = __builtin_amdgcn_mfma_f32_32x32x16_f16(a, Cb[si][0], d0, 0, 0, 0);
        d1 = __builtin_amdgcn_mfma_f32_32x32x16_f16(a, Cb[si][1], d1, 0, 0, 0);
    }
    __syncthreads();
    // h2 = relu(d + b2) -> smem[32][268]
    #pragma unroll
    for (int rg = 0; rg < 16; ++rg) {
        const int m = (rg & 3) + 8 * (rg >> 2) + 4 * lq2;
        const float v0 = d0[rg] + b2r0;
        const float v1 = d1[rg] + b2r1;
        smem[m * 268 + nq * 64 + l32]      = (f16)(v0 > 0.f ? v0 : 0.f);
        smem[m * 268 + nq * 64 + 32 + l32] = (f16)(v1 > 0.f ? v1 : 0.f);
    }
    __syncthreads();
    // ---- GEMM3: [32,256]@[256,16] via 16x16x32; waves 0-1
    if (w < 2) {
        f32x4 acc3 = (f32x4){0.f, 0.f, 0.f, 0.f};
        const f16* w3row = W3T + (size_t)l16 * 256 + lq * 8;
        const f16* h2row = smem + (w * 16 + l16) * 268 + lq * 8;
        #pragma unroll
        for (int ks = 0; ks < 8; ++ks) {
            const f16x8 af = *(const f16x8*)(h2row + ks * 32);
            const f16x8 bf = *(const f16x8*)(w3row + ks * 32);
            acc3 = __builtin_amdgcn_mfma_f32_16x16x32_f16(af, bf, acc3, 0, 0, 0);
        }
        const int orow = w * 16 + lq * 4;
        if (!is_speed) {
            if (l16 < 3) {
                const float b3 = bias3[l16];
                #pragma unroll
                for (int r2 = 0; r2 < 4; ++r2) {
                    const int g2 = rowIdx[orow + r2];
                    if (g2 >= 0)
                        out[(size_t)g2 * 3 + l16] = 1.f / (1.f + __expf(-(acc3[r2] + b3)));
                }
            }
        } else if (l16 == 0) {
            const float b3 = bias3[0];
            #pragma unroll
            for (int r2 = 0; r2 < 4; ++r2)
                out[(size_t)3 * B_ROWS + rowIdx[orow + r2]] = acc3[r2] + b3;
        }
    }
}

extern "C" void kernel_launch(void* const* d_in, const int* in_sizes, int n_in,
                              void* d_out, int out_size, void* d_ws, size_t ws_size,
                              hipStream_t stream) {
    (void)in_sizes; (void)n_in; (void)out_size; (void)ws_size;
    const float* embedding = (const float*)d_in[0];
    const float* speed     = (const float*)d_in[1];
    const int*   command   = (const int*)d_in[2];
    const float* si_W1 = (const float*)d_in[3];
    const float* si_b1 = (const float*)d_in[4];
    const float* si_W2 = (const float*)d_in[5];
    const float* si_b2 = (const float*)d_in[6];
    const float* bW1   = (const float*)d_in[7];
    const float* bb1   = (const float*)d_in[8];
    const float* bW2   = (const float*)d_in[9];
    const float* bb2   = (const float*)d_in[10];
    const float* bW3   = (const float*)d_in[11];
    const float* bb3   = (const float*)d_in[12];
    const float* so_W1 = (const float*)d_in[13];
    const float* so_b1 = (const float*)d_in[14];
    const float* so_W2 = (const float*)d_in[15];
    const float* so_b2 = (const float*)d_in[16];
    const float* so_W3 = (const float*)d_in[17];
    const float* so_b3 = (const float*)d_in[18];
    float* out = (float*)d_out;

    char* ws = (char*)d_ws;
    f16* sF16   = (f16*)(ws + OFF_SF16);
    f16* siW2T  = (f16*)(ws + OFF_SIW2T);
    f16* bW1T   = (f16*)(ws + OFF_BW1T);
    f16* bW2T   = (f16*)(ws + OFF_BW2T);
    f16* soW1T  = (f16*)(ws + OFF_SOW1T);
    f16* soW2T  = (f16*)(ws + OFF_SOW2T);
    f16* bW3T16 = (f16*)(ws + OFF_BW3T16);
    f16* soW3T16= (f16*)(ws + OFF_SOW3T16);
    int* counts = (int*)(ws + OFF_COUNTS);
    int* cursors= (int*)(ws + OFF_CURSORS);
    int* tile_cmd = (int*)(ws + OFF_TILECMD);
    int* perm   = (int*)(ws + OFF_PERM);

    prep_kernel<<<1859, dim3(32, 8), 0, stream>>>(
        si_W2, bW1, bW2, so_W1, so_W2, bW3, so_W3,
        siW2T, bW1T, bW2T, soW1T, soW2T, bW3T16, soW3T16,
        counts, cursors, perm);
    speedin_kernel<<<1024, 256, 0, stream>>>(
        speed, si_W1, si_b1, siW2T, si_b2, command, sF16, counts);
    place_kernel<<<256, 256, 0, stream>>>(command, counts, cursors, perm, tile_cmd);
    heads_kernel<<<NT_SP32 + NT_BR32, 256, 0, stream>>>(
        embedding, sF16, perm, tile_cmd,
        bW1T, bW2T, bW3T16, bb1, bb2, bb3,
        soW1T, soW2T, soW3T16, so_b1, so_b2, so_b3, out);
}